// Round 5
// baseline (117.217 us; speedup 1.0000x reference)
//
#include <hip/hip_runtime.h>

// RhythmNetLoss: out = mean(|a-b|) + 150 * mean(|x - mean(x)|), x = a[:6].flatten()
// a,b: (8192,4096) fp32. Output: 1 fp32 scalar.
// Single fused kernel: 2048 L1-partial blocks + 1 smooth block; the last block
// to finish (ticket) reduces the partials and writes the scalar.

#define N_TOTAL  (8192 * 4096)
#define N_SMOOTH (6 * 4096)
#define LAMBDA_F 150.0f

constexpr int BLOCKS  = 2048;             // main L1 blocks (block BLOCKS = smooth)
constexpr int THREADS = 256;
constexpr int N4           = N_TOTAL / 4;            // 8388608 float4
constexpr int F4_PER_BLOCK = N4 / BLOCKS;            // 4096 (64 KiB/input/block)
constexpr int ITERS        = F4_PER_BLOCK / THREADS; // 16 float4/thread

typedef float vf4 __attribute__((ext_vector_type(4)));

// Block-wide sum + broadcast. NT = blockDim.x (multiple of 64).
template <int NT>
__device__ __forceinline__ float block_reduce_bcast(float v) {
    __shared__ float ws[NT / 64 + 1];
    __syncthreads();  // protect ws across repeated calls
    #pragma unroll
    for (int off = 32; off > 0; off >>= 1) v += __shfl_down(v, off, 64);
    const int lane = threadIdx.x & 63;
    const int wid  = threadIdx.x >> 6;
    if (lane == 0) ws[wid] = v;
    __syncthreads();
    if (threadIdx.x == 0) {
        float s = 0.0f;
        #pragma unroll
        for (int w = 0; w < NT / 64; ++w) s += ws[w];
        ws[NT / 64] = s;
    }
    __syncthreads();
    return ws[NT / 64];
}

__device__ __forceinline__ float abs4(vf4 va, vf4 vb) {
    return fabsf(va.x - vb.x) + fabsf(va.y - vb.y) +
           fabsf(va.z - vb.z) + fabsf(va.w - vb.w);
}

__device__ __forceinline__ float l1_chunk(const vf4* __restrict__ a,
                                          const vf4* __restrict__ b) {
    const int base = blockIdx.x * F4_PER_BLOCK + threadIdx.x;
    float s0 = 0.0f, s1 = 0.0f, s2 = 0.0f, s3 = 0.0f;
    #pragma unroll
    for (int g = 0; g < ITERS / 4; ++g) {
        const int i0 = base + (g * 4 + 0) * THREADS;
        const int i1 = base + (g * 4 + 1) * THREADS;
        const int i2 = base + (g * 4 + 2) * THREADS;
        const int i3 = base + (g * 4 + 3) * THREADS;
        vf4 a0 = a[i0]; vf4 a1 = a[i1]; vf4 a2 = a[i2]; vf4 a3 = a[i3];
        vf4 b0 = b[i0]; vf4 b1 = b[i1]; vf4 b2 = b[i2]; vf4 b3 = b[i3];
        s0 += abs4(a0, b0);
        s1 += abs4(a1, b1);
        s2 += abs4(a2, b2);
        s3 += abs4(a3, b3);
    }
    return (s0 + s1) + (s2 + s3);
}

__global__ __launch_bounds__(THREADS) void rhythm_loss_kernel(
    const vf4* __restrict__ a, const vf4* __restrict__ b,
    float* __restrict__ partial, unsigned* __restrict__ ticket,
    float* __restrict__ out) {
    const int bid = blockIdx.x;

    if (bid < BLOCKS) {
        float bs = block_reduce_bcast<THREADS>(l1_chunk(a, b));
        if (threadIdx.x == 0) {
            // agent-scope store: lands at the device coherence point (past
            // this XCD's L2) so the finisher block can read it safely.
            __hip_atomic_store(&partial[bid], bs, __ATOMIC_RELAXED,
                               __HIP_MEMORY_SCOPE_AGENT);
        }
    } else {
        // smooth term: x = first 24576 floats of a (tiny, cached)
        constexpr int NS4 = N_SMOOTH / 4;  // 6144 float4
        float xs = 0.0f;
        for (int i = threadIdx.x; i < NS4; i += THREADS) {
            vf4 v = a[i];
            xs += (v.x + v.y) + (v.z + v.w);
        }
        float x_mean = block_reduce_bcast<THREADS>(xs) / (float)N_SMOOTH;
        float ds = 0.0f;
        for (int i = threadIdx.x; i < NS4; i += THREADS) {
            vf4 v = a[i];
            ds += fabsf(v.x - x_mean) + fabsf(v.y - x_mean) +
                  fabsf(v.z - x_mean) + fabsf(v.w - x_mean);
        }
        float dev_sum = block_reduce_bcast<THREADS>(ds);
        if (threadIdx.x == 0) {
            __hip_atomic_store(&partial[BLOCKS], dev_sum, __ATOMIC_RELAXED,
                               __HIP_MEMORY_SCOPE_AGENT);
        }
    }

    // Last-block-finishes protocol.
    __shared__ unsigned last;
    if (threadIdx.x == 0) {
        __threadfence();                       // order partial store before ticket
        unsigned old = atomicAdd(ticket, 1u);  // device-scope by default
        last = (old == (unsigned)BLOCKS) ? 1u : 0u;  // grid = BLOCKS+1
    }
    __syncthreads();
    if (last) {
        float s = 0.0f;
        #pragma unroll
        for (int i = threadIdx.x; i < BLOCKS; i += THREADS)
            s += __hip_atomic_load(&partial[i], __ATOMIC_RELAXED,
                                   __HIP_MEMORY_SCOPE_AGENT);
        float l1_sum = block_reduce_bcast<THREADS>(s);
        if (threadIdx.x == 0) {
            float dev_sum = __hip_atomic_load(&partial[BLOCKS], __ATOMIC_RELAXED,
                                              __HIP_MEMORY_SCOPE_AGENT);
            out[0] = l1_sum / (float)N_TOTAL + LAMBDA_F * (dev_sum / (float)N_SMOOTH);
        }
    }
}

extern "C" void kernel_launch(void* const* d_in, const int* in_sizes, int n_in,
                              void* d_out, int out_size, void* d_ws, size_t ws_size,
                              hipStream_t stream) {
    const float* gru = (const float*)d_in[0];
    const float* tgt = (const float*)d_in[1];
    float* out     = (float*)d_out;
    float* partial = (float*)d_ws;                          // 2049 floats
    unsigned* ticket = (unsigned*)((char*)d_ws + 8448);     // past partials, aligned

    hipMemsetAsync(ticket, 0, sizeof(unsigned), stream);    // graph-capture-legal
    rhythm_loss_kernel<<<BLOCKS + 1, THREADS, 0, stream>>>(
        (const vf4*)gru, (const vf4*)tgt, partial, ticket, out);
}

// Round 6
// 52.274 us; speedup vs baseline: 2.2424x; 2.2424x over previous
//
#include <hip/hip_runtime.h>

// RhythmNetLoss: out = mean(|a-b|) + 150 * mean(|x - mean(x)|), x = a[:6].flatten()
// a,b: (8192,4096) fp32. Output: 1 fp32 scalar.
// Single kernel: 2048 L1 blocks + 1 smooth block; each block atomicAdds its
// pre-scaled contribution into out[0] (zeroed by a memset graph node).

#define N_TOTAL  (8192 * 4096)
#define N_SMOOTH (6 * 4096)
#define LAMBDA_F 150.0f

constexpr int BLOCKS  = 2048;             // main L1 blocks (block BLOCKS = smooth)
constexpr int THREADS = 256;
constexpr int N4           = N_TOTAL / 4;            // 8388608 float4
constexpr int F4_PER_BLOCK = N4 / BLOCKS;            // 4096 (64 KiB/input/block)
constexpr int ITERS        = F4_PER_BLOCK / THREADS; // 16 float4/thread

typedef float vf4 __attribute__((ext_vector_type(4)));

// Block-wide sum + broadcast. NT = blockDim.x (multiple of 64).
template <int NT>
__device__ __forceinline__ float block_reduce_bcast(float v) {
    __shared__ float ws[NT / 64 + 1];
    __syncthreads();  // protect ws across repeated calls
    #pragma unroll
    for (int off = 32; off > 0; off >>= 1) v += __shfl_down(v, off, 64);
    const int lane = threadIdx.x & 63;
    const int wid  = threadIdx.x >> 6;
    if (lane == 0) ws[wid] = v;
    __syncthreads();
    if (threadIdx.x == 0) {
        float s = 0.0f;
        #pragma unroll
        for (int w = 0; w < NT / 64; ++w) s += ws[w];
        ws[NT / 64] = s;
    }
    __syncthreads();
    return ws[NT / 64];
}

__device__ __forceinline__ float abs4(vf4 va, vf4 vb) {
    return fabsf(va.x - vb.x) + fabsf(va.y - vb.y) +
           fabsf(va.z - vb.z) + fabsf(va.w - vb.w);
}

__device__ __forceinline__ float l1_chunk(const vf4* __restrict__ a,
                                          const vf4* __restrict__ b) {
    const int base = blockIdx.x * F4_PER_BLOCK + threadIdx.x;
    float s0 = 0.0f, s1 = 0.0f, s2 = 0.0f, s3 = 0.0f;
    #pragma unroll
    for (int g = 0; g < ITERS / 4; ++g) {
        const int i0 = base + (g * 4 + 0) * THREADS;
        const int i1 = base + (g * 4 + 1) * THREADS;
        const int i2 = base + (g * 4 + 2) * THREADS;
        const int i3 = base + (g * 4 + 3) * THREADS;
        vf4 a0 = a[i0]; vf4 a1 = a[i1]; vf4 a2 = a[i2]; vf4 a3 = a[i3];
        vf4 b0 = b[i0]; vf4 b1 = b[i1]; vf4 b2 = b[i2]; vf4 b3 = b[i3];
        s0 += abs4(a0, b0);
        s1 += abs4(a1, b1);
        s2 += abs4(a2, b2);
        s3 += abs4(a3, b3);
    }
    return (s0 + s1) + (s2 + s3);
}

__global__ __launch_bounds__(THREADS) void rhythm_loss_kernel(
    const vf4* __restrict__ a, const vf4* __restrict__ b,
    float* __restrict__ out) {
    if (blockIdx.x < BLOCKS) {
        float bs = block_reduce_bcast<THREADS>(l1_chunk(a, b));
        if (threadIdx.x == 0)
            atomicAdd(out, bs * (1.0f / (float)N_TOTAL));
    } else {
        // smooth term: x = first 24576 floats of a (tiny, cached)
        constexpr int NS4 = N_SMOOTH / 4;  // 6144 float4
        float xs = 0.0f;
        for (int i = threadIdx.x; i < NS4; i += THREADS) {
            vf4 v = a[i];
            xs += (v.x + v.y) + (v.z + v.w);
        }
        float x_mean = block_reduce_bcast<THREADS>(xs) / (float)N_SMOOTH;
        float ds = 0.0f;
        for (int i = threadIdx.x; i < NS4; i += THREADS) {
            vf4 v = a[i];
            ds += fabsf(v.x - x_mean) + fabsf(v.y - x_mean) +
                  fabsf(v.z - x_mean) + fabsf(v.w - x_mean);
        }
        float dev_sum = block_reduce_bcast<THREADS>(ds);
        if (threadIdx.x == 0)
            atomicAdd(out, LAMBDA_F * dev_sum * (1.0f / (float)N_SMOOTH));
    }
}

extern "C" void kernel_launch(void* const* d_in, const int* in_sizes, int n_in,
                              void* d_out, int out_size, void* d_ws, size_t ws_size,
                              hipStream_t stream) {
    const float* gru = (const float*)d_in[0];
    const float* tgt = (const float*)d_in[1];
    float* out = (float*)d_out;

    hipMemsetAsync(out, 0, sizeof(float), stream);  // graph-capture-legal
    rhythm_loss_kernel<<<BLOCKS + 1, THREADS, 0, stream>>>(
        (const vf4*)gru, (const vf4*)tgt, out);
}

// Round 7
// 48.156 us; speedup vs baseline: 2.4341x; 1.0855x over previous
//
#include <hip/hip_runtime.h>

// RhythmNetLoss: out = mean(|a-b|) + 150 * mean(|x - mean(x)|), x = a[:6].flatten()
// a,b: (8192,4096) fp32. Output: 1 fp32 scalar.
// Best-measured structure (R2): streaming partial-sum kernel + tiny finalize.
// Fusion variants (fence-based, atomic-based) both measured SLOWER — keep split.

#define N_TOTAL  (8192 * 4096)
#define N_SMOOTH (6 * 4096)
#define LAMBDA_F 150.0f

constexpr int BLOCKS  = 2048;
constexpr int THREADS = 256;
constexpr int N4           = N_TOTAL / 4;            // 8388608 float4
constexpr int F4_PER_BLOCK = N4 / BLOCKS;            // 4096 (64 KiB/input/block)
constexpr int ITERS        = F4_PER_BLOCK / THREADS; // 16 float4/thread
constexpr int FT = 1024;                             // finalize block size

typedef float vf4 __attribute__((ext_vector_type(4)));

// Block-wide sum + broadcast. NT = blockDim.x (multiple of 64).
template <int NT>
__device__ __forceinline__ float block_reduce_bcast(float v) {
    __shared__ float ws[NT / 64 + 1];
    __syncthreads();  // protect ws across repeated calls
    #pragma unroll
    for (int off = 32; off > 0; off >>= 1) v += __shfl_down(v, off, 64);
    const int lane = threadIdx.x & 63;
    const int wid  = threadIdx.x >> 6;
    if (lane == 0) ws[wid] = v;
    __syncthreads();
    if (threadIdx.x == 0) {
        float s = 0.0f;
        #pragma unroll
        for (int w = 0; w < NT / 64; ++w) s += ws[w];
        ws[NT / 64] = s;
    }
    __syncthreads();
    return ws[NT / 64];
}

__device__ __forceinline__ float abs4(vf4 va, vf4 vb) {
    return fabsf(va.x - vb.x) + fabsf(va.y - vb.y) +
           fabsf(va.z - vb.z) + fabsf(va.w - vb.w);
}

// Kernel A: partial sums of |a-b|, 4 float4/input in flight per group.
__global__ __launch_bounds__(THREADS) void l1_partial_kernel(
    const vf4* __restrict__ a, const vf4* __restrict__ b,
    float* __restrict__ partial) {
    const int base = blockIdx.x * F4_PER_BLOCK + threadIdx.x;
    float s0 = 0.0f, s1 = 0.0f, s2 = 0.0f, s3 = 0.0f;
    #pragma unroll
    for (int g = 0; g < ITERS / 4; ++g) {
        const int i0 = base + (g * 4 + 0) * THREADS;
        const int i1 = base + (g * 4 + 1) * THREADS;
        const int i2 = base + (g * 4 + 2) * THREADS;
        const int i3 = base + (g * 4 + 3) * THREADS;
        vf4 a0 = a[i0]; vf4 a1 = a[i1]; vf4 a2 = a[i2]; vf4 a3 = a[i3];
        vf4 b0 = b[i0]; vf4 b1 = b[i1]; vf4 b2 = b[i2]; vf4 b3 = b[i3];
        s0 += abs4(a0, b0);
        s1 += abs4(a1, b1);
        s2 += abs4(a2, b2);
        s3 += abs4(a3, b3);
    }
    float bs = block_reduce_bcast<THREADS>((s0 + s1) + (s2 + s3));
    if (threadIdx.x == 0) partial[blockIdx.x] = bs;
}

// Kernel B: reduce partials; two vectorized passes over first 6 rows; write scalar.
__global__ __launch_bounds__(FT) void finalize_kernel(
    const float* __restrict__ partial, const float* __restrict__ gru,
    float* __restrict__ out) {
    // 1) total |a-b| sum
    float s = 0.0f;
    #pragma unroll
    for (int i = threadIdx.x; i < BLOCKS; i += FT) s += partial[i];
    float l1_sum = block_reduce_bcast<FT>(s);

    // 2) mean of x = gru[0 : 24576], float4-vectorized
    const vf4* x4 = (const vf4*)gru;
    constexpr int NS4 = N_SMOOTH / 4;  // 6144
    float xs = 0.0f;
    #pragma unroll
    for (int i = threadIdx.x; i < NS4; i += FT) {
        vf4 v = x4[i];
        xs += (v.x + v.y) + (v.z + v.w);
    }
    float x_mean = block_reduce_bcast<FT>(xs) / (float)N_SMOOTH;

    // 3) sum |x - mean| (x now cache-resident)
    float ds = 0.0f;
    #pragma unroll
    for (int i = threadIdx.x; i < NS4; i += FT) {
        vf4 v = x4[i];
        ds += fabsf(v.x - x_mean) + fabsf(v.y - x_mean) +
              fabsf(v.z - x_mean) + fabsf(v.w - x_mean);
    }
    float dev_sum = block_reduce_bcast<FT>(ds);

    if (threadIdx.x == 0) {
        out[0] = l1_sum / (float)N_TOTAL + LAMBDA_F * (dev_sum / (float)N_SMOOTH);
    }
}

extern "C" void kernel_launch(void* const* d_in, const int* in_sizes, int n_in,
                              void* d_out, int out_size, void* d_ws, size_t ws_size,
                              hipStream_t stream) {
    const float* gru = (const float*)d_in[0];
    const float* tgt = (const float*)d_in[1];
    float* out     = (float*)d_out;
    float* partial = (float*)d_ws;  // BLOCKS floats = 8 KB

    l1_partial_kernel<<<BLOCKS, THREADS, 0, stream>>>(
        (const vf4*)gru, (const vf4*)tgt, partial);
    finalize_kernel<<<1, FT, 0, stream>>>(partial, gru, out);
}